// Round 12
// baseline (131.183 us; speedup 1.0000x reference)
//
#include <hip/hip_runtime.h>
#include <math.h>

// Problem dims
#define BB 512
#define DE 1024
#define DM 1024
#define NA 512
#define NP 256

typedef unsigned short ushort_t;
typedef __attribute__((ext_vector_type(8))) short s8v;   // 8 bf16 (4 VGPRs)
typedef __attribute__((ext_vector_type(4))) float f4v;   // 4 fp32 acc

static __device__ __forceinline__ float4 ld4(const float* p) {
    return *reinterpret_cast<const float4*>(p);
}
static __device__ __forceinline__ void ld8(const float* p, float* d) {
    float4 a = ld4(p), b = ld4(p + 4);
    d[0]=a.x; d[1]=a.y; d[2]=a.z; d[3]=a.w;
    d[4]=b.x; d[5]=b.y; d[6]=b.z; d[7]=b.w;
}

// RNE float -> bf16 bits
__device__ __forceinline__ unsigned bf16h(float x) {
    unsigned u = __float_as_uint(x);
    return (u + 0x7FFFu + ((u >> 16) & 1u)) >> 16;
}
__device__ __forceinline__ float bf16f(unsigned h) { return __uint_as_float(h << 16); }

__device__ __forceinline__ f4v mfma16(s8v a, s8v b, f4v c) {
    return __builtin_amdgcn_mfma_f32_16x16x32_bf16(a, b, c, 0, 0, 0);
}

// Barrier WITHOUT the vmcnt(0) drain (lgkmcnt only — prefetch stays in flight).
__device__ __forceinline__ void softbar() {
    asm volatile("s_waitcnt lgkmcnt(0)" ::: "memory");
    __builtin_amdgcn_s_barrier();
    __builtin_amdgcn_sched_barrier(0);
}

// ================= PREP: PE table (fp32) + weight/h_s hi-lo splits ============
__device__ __forceinline__ void d_ew(const float* __restrict__ W,
                                     ushort_t* __restrict__ Hh,
                                     ushort_t* __restrict__ Hl, int bid) {
    int i = (bid * 256 + threadIdx.x) * 4;
    float4 f = ld4(W + i);
    float ff[4] = {f.x, f.y, f.z, f.w};
    unsigned h[4], l[4];
    #pragma unroll
    for (int q = 0; q < 4; ++q) { h[q] = bf16h(ff[q]); l[q] = bf16h(ff[q] - bf16f(h[q])); }
    *reinterpret_cast<uint2*>(Hh + i) = make_uint2(h[0] | (h[1] << 16), h[2] | (h[3] << 16));
    *reinterpret_cast<uint2*>(Hl + i) = make_uint2(l[0] | (l[1] << 16), l[2] | (l[3] << 16));
}

__device__ __forceinline__ void d_tr(const float* __restrict__ W,
                                     ushort_t* __restrict__ Th,
                                     ushort_t* __restrict__ Tl,
                                     int K, int N, int bid) {
    __shared__ float t[32][33];
    int ntn = N >> 5;
    int kt = bid / ntn, nt = bid - kt * ntn;
    int k0 = kt * 32, n0 = nt * 32;
    int ty = threadIdx.x >> 3, tx = (threadIdx.x & 7) * 4;
    float4 f = ld4(W + (size_t)(k0 + ty) * N + n0 + tx);
    t[ty][tx] = f.x; t[ty][tx + 1] = f.y; t[ty][tx + 2] = f.z; t[ty][tx + 3] = f.w;
    __syncthreads();
    unsigned h[4], l[4];
    #pragma unroll
    for (int q = 0; q < 4; ++q) {
        float x = t[tx + q][ty];
        h[q] = bf16h(x); l[q] = bf16h(x - bf16f(h[q]));
    }
    size_t o = (size_t)(n0 + ty) * K + k0 + tx;
    *reinterpret_cast<uint2*>(Th + o) = make_uint2(h[0] | (h[1] << 16), h[2] | (h[3] << 16));
    *reinterpret_cast<uint2*>(Tl + o) = make_uint2(l[0] | (l[1] << 16), l[2] | (l[3] << 16));
}

__global__ __launch_bounds__(256) void prep(
    const float* __restrict__ h_s, const float* __restrict__ WQo,
    const float* __restrict__ WQi, const float* __restrict__ WKo,
    const float* __restrict__ WKi, const float* __restrict__ WVi,
    const float* __restrict__ W1, const float* __restrict__ W2,
    float* pef, ushort_t* hsh, ushort_t* hsl,
    ushort_t* WQoh, ushort_t* WQol, ushort_t* WQih, ushort_t* WQil,
    ushort_t* WKoh, ushort_t* WKol, ushort_t* WKih, ushort_t* WKil,
    ushort_t* WVih, ushort_t* WVil, ushort_t* W1th, ushort_t* W1tl,
    ushort_t* W2th, ushort_t* W2tl) {
    int bid = blockIdx.x;
    if (bid < 257) {
        int p = bid, i = threadIdx.x;
        const float c = -0.017988946039015984f; // -ln(10000)/512
        float div = expf((float)(2 * i) * c);
        float arg = (float)p * div;
        float2 scv = make_float2(sinf(arg), cosf(arg));
        *reinterpret_cast<float2*>(pef + p * NA + 2 * i) = scv;
        return;
    }
    if ((bid -= 257) < 512)  { d_ew(h_s, hsh, hsl, bid); return; }
    if ((bid -= 512) < 1024) { d_ew(WQo, WQoh, WQol, bid); return; }
    if ((bid -= 1024) < 1024){ d_ew(WQi, WQih, WQil, bid); return; }
    if ((bid -= 1024) < 512) { d_ew(WKo, WKoh, WKol, bid); return; }
    if ((bid -= 512) < 512)  { d_ew(WKi, WKih, WKil, bid); return; }
    if ((bid -= 512) < 512)  { d_ew(WVi, WVih, WVil, bid); return; }
    if ((bid -= 512) < 2048) { d_tr(W1, W1th, W1tl, DE + DM, DM, bid); return; }
    bid -= 2048;               d_tr(W2, W2th, W2tl, DM, NA, bid);
}

// ================= split-bf16 MFMA GEMM tile (all-static dims) ================
template<int M, int N, int K, int KS, int LDA, int LDA2, int LDB, int LDB2,
         int LDC, int BIAS, int RELU, int CFOUT, int CHOUT, int ADDC>
__device__ __forceinline__ void gtile(
    const ushort_t* __restrict__ Ah, const ushort_t* __restrict__ Al,
    const ushort_t* __restrict__ A2h, const ushort_t* __restrict__ A2l,
    const ushort_t* __restrict__ Bh, const ushort_t* __restrict__ Bl,
    const ushort_t* __restrict__ B2h, const ushort_t* __restrict__ B2l,
    const float* __restrict__ bias, const float* __restrict__ Cin,
    float* __restrict__ Cf, ushort_t* __restrict__ Ch, ushort_t* __restrict__ Cl,
    ushort_t* sAh, ushort_t* sAl, ushort_t* sBh, ushort_t* sBl) {
    const int row0 = blockIdx.y * 32, col0 = blockIdx.x * 64;
    if (row0 >= M || col0 >= N) return;
    const int tid = threadIdx.x;

    const int ar = tid >> 3, ak = (tid & 7) * 8;
    const int asi = ar * 64 + (ak ^ ((ar & 7) << 3));
    const int br = tid >> 2, bk = (tid & 3) * 16;
    const int bsw = (br & 7) << 3;
    const int bsi0 = br * 64 + (bk ^ bsw);
    const int bsi1 = br * 64 + ((bk + 8) ^ bsw);

    const int wid = tid >> 6, lane = tid & 63;
    const int wm = wid & 1, wn = wid >> 1;
    const int lm = lane & 15, lk = lane >> 4;
    const int ra = wm * 16 + lm;
    const int rb = wn * 32 + lm;
    const int aswz = (ra & 7) << 3;
    const int bswz = (rb & 7) << 3;

    int4 rah, ral, rb0h, rb1h, rb0l, rb1l;
    auto load = [&](int k0) {
        if (KS < K && k0 >= KS) {
            size_t ao = (size_t)(row0 + ar) * LDA2 + (k0 - KS) + ak;
            rah = *reinterpret_cast<const int4*>(A2h + ao);
            ral = *reinterpret_cast<const int4*>(A2l + ao);
        } else {
            size_t ao = (size_t)(row0 + ar) * LDA + k0 + ak;
            rah = *reinterpret_cast<const int4*>(Ah + ao);
            ral = *reinterpret_cast<const int4*>(Al + ao);
        }
        if (KS < K && k0 >= KS) {
            size_t bo = (size_t)(col0 + br) * LDB2 + (k0 - KS) + bk;
            rb0h = *reinterpret_cast<const int4*>(B2h + bo);
            rb1h = *reinterpret_cast<const int4*>(B2h + bo + 8);
            rb0l = *reinterpret_cast<const int4*>(B2l + bo);
            rb1l = *reinterpret_cast<const int4*>(B2l + bo + 8);
        } else {
            size_t bo = (size_t)(col0 + br) * LDB + k0 + bk;
            rb0h = *reinterpret_cast<const int4*>(Bh + bo);
            rb1h = *reinterpret_cast<const int4*>(Bh + bo + 8);
            rb0l = *reinterpret_cast<const int4*>(Bl + bo);
            rb1l = *reinterpret_cast<const int4*>(Bl + bo + 8);
        }
    };

    f4v acc[2] = {};
    load(0);
    constexpr int NT = K >> 6;
    #pragma unroll
    for (int t = 0; t < NT; ++t) {
        const int co = (t & 1) ? 2048 : 0;
        const int cb = (t & 1) ? 4096 : 0;
        *reinterpret_cast<int4*>(&sAh[co + asi]) = rah;
        *reinterpret_cast<int4*>(&sAl[co + asi]) = ral;
        *reinterpret_cast<int4*>(&sBh[cb + bsi0]) = rb0h;
        *reinterpret_cast<int4*>(&sBh[cb + bsi1]) = rb1h;
        *reinterpret_cast<int4*>(&sBl[cb + bsi0]) = rb0l;
        *reinterpret_cast<int4*>(&sBl[cb + bsi1]) = rb1l;
        if (t + 1 < NT) load((t + 1) << 6);
        softbar();   // lgkmcnt(0)+s_barrier only: prefetch stays in flight
        #pragma unroll
        for (int ks = 0; ks < 2; ++ks) {
            const int ka = (ks * 32 + lk * 8) ^ aswz;
            const int kb = (ks * 32 + lk * 8) ^ bswz;
            s8v a_h = *reinterpret_cast<const s8v*>(&sAh[co + ra * 64 + ka]);
            s8v a_l = *reinterpret_cast<const s8v*>(&sAl[co + ra * 64 + ka]);
            s8v b0h = *reinterpret_cast<const s8v*>(&sBh[cb + rb * 64 + kb]);
            s8v b1h = *reinterpret_cast<const s8v*>(&sBh[cb + (rb + 16) * 64 + kb]);
            s8v b0l = *reinterpret_cast<const s8v*>(&sBl[cb + rb * 64 + kb]);
            s8v b1l = *reinterpret_cast<const s8v*>(&sBl[cb + (rb + 16) * 64 + kb]);
            acc[0] = mfma16(a_h, b0h, acc[0]);
            acc[1] = mfma16(a_h, b1h, acc[1]);
            acc[0] = mfma16(a_h, b0l, acc[0]);
            acc[1] = mfma16(a_h, b1l, acc[1]);
            acc[0] = mfma16(a_l, b0h, acc[0]);
            acc[1] = mfma16(a_l, b1h, acc[1]);
        }
    }

    #pragma unroll
    for (int j = 0; j < 2; ++j) {
        int gc = col0 + wn * 32 + j * 16 + lm;
        float bv = BIAS ? bias[gc] : 0.0f;
        #pragma unroll
        for (int r = 0; r < 4; ++r) {
            int gr = row0 + wm * 16 + lk * 4 + r;
            size_t o = (size_t)gr * LDC + gc;
            float val = acc[j][r] + bv;
            if (ADDC) val += Cin[o];
            if (RELU) val = fmaxf(val, 0.0f);
            if (CFOUT) Cf[o] = val;
            if (CHOUT) {
                unsigned h = bf16h(val);
                Ch[o] = (ushort_t)h;
                Cl[o] = (ushort_t)bf16h(val - bf16f(h));
            }
        }
    }
}

#define GSHARED \
    __shared__ ushort_t sAh[2 * 2048], sAl[2 * 2048]; \
    __shared__ ushort_t sBh[2 * 4096], sBl[2 * 4096];

// ---- weight batch: z0/z1: Wc = WK@WQ^T; z2: Wv1t; z3: H1 = h_s@W1a^T --------
__global__ __launch_bounds__(256) void wbatch(
    const ushort_t* WKoh, const ushort_t* WKol,
    const ushort_t* WKih, const ushort_t* WKil,
    const ushort_t* WQoh, const ushort_t* WQol,
    const ushort_t* WQih, const ushort_t* WQil,
    const ushort_t* W1th, const ushort_t* W1tl,
    const ushort_t* WVih, const ushort_t* WVil,
    const ushort_t* hsh, const ushort_t* hsl,
    ushort_t* Wbigh, ushort_t* Wbigl,
    ushort_t* Wv1th, ushort_t* Wv1tl, float* H1) {
    GSHARED
    const int z = blockIdx.z;
    if (z == 3) {
        gtile<512, 1024, 1024, 1024, 1024, 1, 2048, 1, 1024, 0,0,1,0,0>(
            hsh, hsl, nullptr, nullptr, W1th, W1tl, nullptr, nullptr,
            nullptr, nullptr, H1, nullptr, nullptr, sAh, sAl, sBh, sBl);
    } else if (z == 2) {
        gtile<1024, 512, 1024, 1024, 2048, 1, 1024, 1, 512, 0,0,0,1,0>(
            W1th + 1024, W1tl + 1024, nullptr, nullptr,
            WVih, WVil, nullptr, nullptr,
            nullptr, nullptr, nullptr, Wv1th, Wv1tl, sAh, sAl, sBh, sBl);
    } else {
        const ushort_t* Ah = z ? WKih : WKoh;
        const ushort_t* Al = z ? WKil : WKol;
        const ushort_t* Bh = z ? WQih : WQoh;
        const ushort_t* Bl = z ? WQil : WQol;
        ushort_t* Ch = Wbigh + (size_t)z * 512 * 1024;
        ushort_t* Cl = Wbigl + (size_t)z * 512 * 1024;
        gtile<512, 1024, 1024, 1024, 1024, 1, 1024, 1, 1024, 0,0,0,1,0>(
            Ah, Al, nullptr, nullptr, Bh, Bl, nullptr, nullptr,
            nullptr, nullptr, nullptr, Ch, Cl, sAh, sAl, sBh, sBl);
    }
}

// ---- ubatch: Up[z] = h_s[:,z*512:] @ Wbig[:,z*512:]^T (fp32 partials) --------
__global__ __launch_bounds__(256) void ubatch(
    const ushort_t* hsh, const ushort_t* hsl,
    const ushort_t* Wbigh, const ushort_t* Wbigl,
    float* Up) {
    GSHARED
    const int z = blockIdx.z;
    gtile<512, 1024, 512, 512, 1024, 1, 1024, 1, 1024, 0,0,1,0,0>(
        hsh + z * 512, hsl + z * 512, nullptr, nullptr,
        Wbigh + z * 512, Wbigl + z * 512, nullptr, nullptr,
        nullptr, nullptr, Up + (size_t)z * 512 * 1024, nullptr, nullptr,
        sAh, sAl, sBh, sBl);
}

// ---- hidden = relu(H1 + w@Wv1t^T + b1) (512x1024x512) ------------------------
__global__ __launch_bounds__(256) void hgemm(
    const ushort_t* wh, const ushort_t* wl,
    const ushort_t* Wv1th, const ushort_t* Wv1tl,
    const float* b1, const float* H1,
    ushort_t* hidh, ushort_t* hidl) {
    GSHARED
    gtile<512, 1024, 512, 512, 512, 1, 512, 1, 1024, 1,1,0,1,1>(
        wh, wl, nullptr, nullptr, Wv1th, Wv1tl, nullptr, nullptr,
        b1, H1, nullptr, hidh, hidl, sAh, sAl, sBh, sBl);
}

// ---- lgemm split-K2: Lp[z] = hidden[:,z*512:] @ W2t[:,z*512:]^T (fp32) -------
__global__ __launch_bounds__(256) void lgemm(
    const ushort_t* hidh, const ushort_t* hidl,
    const ushort_t* W2th, const ushort_t* W2tl,
    float* Lp) {
    GSHARED
    const int z = blockIdx.z;
    gtile<512, 512, 512, 512, 1024, 1, 1024, 1, 512, 0,0,1,0,0>(
        hidh + z * 512, hidl + z * 512, nullptr, nullptr,
        W2th + z * 512, W2tl + z * 512, nullptr, nullptr,
        nullptr, nullptr, Lp + (size_t)z * 512 * 512, nullptr, nullptr,
        sAh, sAl, sBh, sBl);
}

// ================= fused attention over phi (barrier-free stream) =============
// pe-dots hoisted to a per-block prologue table (spo/spi in LDS); main loop is
// pure phi streaming with 2-chunk-deep register prefetch.
__global__ __launch_bounds__(512, 4) void phi_attn(
    const float* __restrict__ phi, const float* __restrict__ Up,
    const float* __restrict__ pe, float* __restrict__ v,
    ushort_t* __restrict__ wh, ushort_t* __restrict__ wl) {
    __shared__ float sva[8][512];   // 16 KB
    __shared__ float ssa[8][512];   // 16 KB
    __shared__ float spo[257], spi[257];   // pe-dot tables
    __shared__ float smx[4][8];
    __shared__ float sred[8];
    const int b = blockIdx.x, tid = threadIdx.x;
    const int wave = tid >> 6, lane = tid & 63;
    const float sc = 0.03125f * 1.4426950408889634f;  // 1/sqrt(dm) * log2(e)

    const float* ub0 = Up + (size_t)b * 1024;
    const float* ub1 = ub0 + (size_t)512 * 1024;
    float u8o[8], u8i[8];
    {
        float t0[8], t1[8];
        ld8(ub0 + lane * 8, t0); ld8(ub1 + lane * 8, t1);
        #pragma unroll
        for (int j = 0; j < 8; ++j) u8o[j] = t0[j] + t1[j];
        ld8(ub0 + 512 + lane * 8, t0); ld8(ub1 + 512 + lane * 8, t1);
        #pragma unroll
        for (int j = 0; j < 8; ++j) u8i[j] = t0[j] + t1[j];
    }
    const float* pb = phi + (size_t)b * NP * NA;

    // ---- prologue: spo[r] = u_out.pe[r], spi[r] = u_in.pe[r] (r = 0..256) ----
    for (int r = wave; r < 257; r += 8) {
        float p8[8];
        ld8(pe + (size_t)r * NA + lane * 8, p8);
        float d0 = 0.f, d1 = 0.f;
        #pragma unroll
        for (int j = 0; j < 8; ++j) {
            d0 = fmaf(u8o[j], p8[j], d0);
            d1 = fmaf(u8i[j], p8[j], d1);
        }
        for (int off = 32; off; off >>= 1) {
            d0 += __shfl_xor(d0, off);
            d1 += __shfl_xor(d1, off);
        }
        if (lane == 0) { spo[r] = d0; spi[r] = d1; }
    }

    // preload chunks 0 and 1 (this wave's 2 rows each)
    float x0[8], x1[8], y0[8], y1[8];
    {
        const float* r = pb + (size_t)(wave * 2) * NA + lane * 8;
        ld8(r, x0); ld8(r + NA, x1);
        const float* r2 = pb + (size_t)(16 + wave * 2) * NA + lane * 8;
        ld8(r2, y0); ld8(r2 + NA, y1);
    }
    __syncthreads();   // spo/spi visible

    float mo = -3.0e38f, mi = -3.0e38f, Zo = 0.f, Zi = 0.f;
    float va[8] = {}, Sa[8] = {};

    for (int c = 0; c < 16; ++c) {
        const int n0 = c * 16 + wave * 2;
        // ---- score current chunk (pure phi dots; pe via table) ----
        float d00 = 0.f, d10 = 0.f, d01 = 0.f, d11 = 0.f;
        #pragma unroll
        for (int j = 0; j < 8; ++j) {
            d00 = fmaf(u8o[j], x0[j], d00);
            d10 = fmaf(u8i[j], x0[j], d10);
            d01 = fmaf(u8o[j], x1[j], d01);
            d11 = fmaf(u8i[j], x1[j], d11);
        }
        for (int off = 32; off; off >>= 1) {
            d00 += __shfl_xor(d00, off); d10 += __shfl_xor(d10, off);
            d01 += __shfl_xor(d01, off); d11 += __shfl_xor(d11, off);
        }
        float so0 = (d00 + spo[n0]) * sc;
        float si0 = (d10 + spi[n0 + 1]) * sc;
        float so1 = (d01 + spo[n0 + 1]) * sc;
        float si1 = (d11 + spi[n0 + 2]) * sc;
        // ---- prefetch chunk c+2 (2-deep: covered by accum + next score) ----
        float z0[8], z1[8];
        if (c < 14) {
            const float* r = pb + (size_t)((c + 2) * 16 + wave * 2) * NA + lane * 8;
            ld8(r, z0); ld8(r + NA, z1);
        }
        // ---- online softmax + accumulate ----
        float nmo = fmaxf(mo, fmaxf(so0, so1));
        float nmi = fmaxf(mi, fmaxf(si0, si1));
        float fo = exp2f(mo - nmo), fi = exp2f(mi - nmi);
        float e00 = exp2f(so0 - nmo), e01 = exp2f(so1 - nmo);
        float e10 = exp2f(si0 - nmi), e11 = exp2f(si1 - nmi);
        mo = nmo; mi = nmi;
        Zo = Zo * fo + (e00 + e01);
        Zi = Zi * fi + (e10 + e11);
        #pragma unroll
        for (int j = 0; j < 8; ++j) {
            va[j] = fmaf(va[j], fo, fmaf(e00, x0[j], e01 * x1[j]));
            Sa[j] = fmaf(Sa[j], fi, fmaf(e10, x0[j], e11 * x1[j]));
        }
        // ---- rotate pipeline ----
        if (c < 15) {
            #pragma unroll
            for (int j = 0; j < 8; ++j) { x0[j] = y0[j]; x1[j] = y1[j]; }
            if (c < 14) {
                #pragma unroll
                for (int j = 0; j < 8; ++j) { y0[j] = z0[j]; y1[j] = z1[j]; }
            }
        }
    }

    // ---- flash merge across the 8 waves ----
    if (lane == 0) { smx[0][wave] = mo; smx[1][wave] = mi; }
    __syncthreads();
    float gmo = smx[0][0], gmi = smx[1][0];
    #pragma unroll
    for (int w2 = 1; w2 < 8; ++w2) {
        gmo = fmaxf(gmo, smx[0][w2]); gmi = fmaxf(gmi, smx[1][w2]);
    }
    float fo = exp2f(mo - gmo), fi = exp2f(mi - gmi);
    {
        float4 a0 = {va[0]*fo, va[1]*fo, va[2]*fo, va[3]*fo};
        float4 a1 = {va[4]*fo, va[5]*fo, va[6]*fo, va[7]*fo};
        *reinterpret_cast<float4*>(&sva[wave][lane * 8]) = a0;
        *reinterpret_cast<float4*>(&sva[wave][lane * 8 + 4]) = a1;
        float4 s0v = {Sa[0]*fi, Sa[1]*fi, Sa[2]*fi, Sa[3]*fi};
        float4 s1v = {Sa[4]*fi, Sa[5]*fi, Sa[6]*fi, Sa[7]*fi};
        *reinterpret_cast<float4*>(&ssa[wave][lane * 8]) = s0v;
        *reinterpret_cast<float4*>(&ssa[wave][lane * 8 + 4]) = s1v;
    }
    if (lane == 0) { smx[2][wave] = Zo * fo; smx[3][wave] = Zi * fi; }
    __syncthreads();
    float Zot = 0.f, Zit = 0.f;
    #pragma unroll
    for (int w2 = 0; w2 < 8; ++w2) { Zot += smx[2][w2]; Zit += smx[3][w2]; }
    float vs = 0.f, Ss = 0.f;
    #pragma unroll
    for (int w2 = 0; w2 < 8; ++w2) { vs += sva[w2][tid]; Ss += ssa[w2][tid]; }
    float vt = vs / Zot;
    v[(size_t)b * NA + tid] = vt;

    // ---- in-head row-0 fixup -> w  (pe-dot term comes from spi[0]) ----
    float uit = ub0[512 + tid] + ub1[512 + tid];
    float part = uit * vt;
    for (int off = 32; off; off >>= 1) part += __shfl_xor(part, off);
    if (lane == 0) sred[wave] = part;
    __syncthreads();
    float dot = ((sred[0] + sred[1]) + (sred[2] + sred[3]))
              + ((sred[4] + sred[5]) + (sred[6] + sred[7]));
    float s0 = (dot + spi[0]) * sc;
    float e0 = exp2f(s0 - gmi);
    float iZ = 1.0f / (Zit + e0);
    float wt = (e0 * vt + Ss) * iZ;
    unsigned h = bf16h(wt);
    wh[(size_t)b * NA + tid] = (ushort_t)h;
    wl[(size_t)b * NA + tid] = (ushort_t)bf16h(wt - bf16f(h));
}

// ---------------- final: out = softmax(v + Lp0 + Lp1 + b2) --------------------
__global__ __launch_bounds__(256) void final_softmax(const float* __restrict__ v,
                                                     const float* __restrict__ Lp,
                                                     const float* __restrict__ b2,
                                                     float* __restrict__ out) {
    __shared__ float smem[4];
    int b = blockIdx.x, t = threadIdx.x;
    int lane = t & 63, w = t >> 6;
    const float* l0 = Lp + (size_t)b * 512;
    const float* l1 = l0 + (size_t)512 * 512;
    float z0 = l0[t] + l1[t] + b2[t] + v[(size_t)b * NA + t];
    float z1 = l0[t + 256] + l1[t + 256] + b2[t + 256] + v[(size_t)b * NA + 256 + t];
    float m = fmaxf(z0, z1);
    for (int off = 32; off; off >>= 1) m = fmaxf(m, __shfl_xor(m, off));
    __syncthreads();
    if (lane == 0) smem[w] = m;
    __syncthreads();
    m = fmaxf(fmaxf(smem[0], smem[1]), fmaxf(smem[2], smem[3]));
    float e0 = expf(z0 - m), e1 = expf(z1 - m);
    float s = e0 + e1;
    for (int off = 32; off; off >>= 1) s += __shfl_xor(s, off);
    __syncthreads();
    if (lane == 0) smem[w] = s;
    __syncthreads();
    float Z = (smem[0] + smem[1]) + (smem[2] + smem[3]);
    out[(size_t)b * NA + t] = e0 / Z;
    out[(size_t)b * NA + 256 + t] = e1 / Z;
}

// ---------------- launch ------------------------------------------------------
extern "C" void kernel_launch(void* const* d_in, const int* in_sizes, int n_in,
                              void* d_out, int out_size, void* d_ws, size_t ws_size,
                              hipStream_t stream) {
    const float* h_s = (const float*)d_in[0];
    const float* phi = (const float*)d_in[1];
    const float* WQo = (const float*)d_in[2];
    const float* WKo = (const float*)d_in[3];
    const float* WQi = (const float*)d_in[4];
    const float* WKi = (const float*)d_in[5];
    const float* WVi = (const float*)d_in[6];
    const float* W1  = (const float*)d_in[7];
    const float* b1  = (const float*)d_in[8];
    const float* W2  = (const float*)d_in[9];
    const float* b2  = (const float*)d_in[10];
    float* out = (float*)d_out;
    float* wsf = (float*)d_ws;

    size_t off = 0;
    auto af = [&](size_t n) { float* p = wsf + off; off += (n + 3) & ~(size_t)3; return p; };
    auto au = [&](size_t n) { ushort_t* p = (ushort_t*)(wsf + off); off += ((n / 2) + 3) & ~(size_t)3; return p; };

    float*    pef   = af(257 * NA);
    ushort_t* hsh   = au((size_t)BB*DE);     ushort_t* hsl   = au((size_t)BB*DE);
    ushort_t* WQoh  = au((size_t)DE*DM);     ushort_t* WQol  = au((size_t)DE*DM);
    ushort_t* WQih  = au((size_t)DE*DM);     ushort_t* WQil  = au((size_t)DE*DM);
    ushort_t* WKoh  = au((size_t)NA*DM);     ushort_t* WKol  = au((size_t)NA*DM);
    ushort_t* WKih  = au((size_t)NA*DM);     ushort_t* WKil  = au((size_t)NA*DM);
    ushort_t* WVih  = au((size_t)NA*DM);     ushort_t* WVil  = au((size_t)NA*DM);
    ushort_t* W1th  = au((size_t)DM*(DE+DM));ushort_t* W1tl  = au((size_t)DM*(DE+DM));
    ushort_t* W2th  = au((size_t)NA*DM);     ushort_t* W2tl  = au((size_t)NA*DM);
    ushort_t* Wbigh = au((size_t)1024*DE);   ushort_t* Wbigl = au((size_t)1024*DE);
    ushort_t* Wv1th = au((size_t)DM*NA);     ushort_t* Wv1tl = au((size_t)DM*NA);
    float*    Up    = af((size_t)2 * BB * 1024);   // ugemm split-K partials
    float*    H1    = af((size_t)BB * DM);         // h_s @ W1a^T
    float*    Lp    = af((size_t)2 * BB * NA);     // lgemm split-K partials
    float*    v     = af((size_t)BB * NA);
    ushort_t* wh    = au((size_t)BB*NA);     ushort_t* wl    = au((size_t)BB*NA);
    ushort_t* hidh  = au((size_t)BB*DM);     ushort_t* hidl  = au((size_t)BB*DM);

    // 1. prep
    prep<<<6913, 256, 0, stream>>>(h_s, WQo, WQi, WKo, WKi, WVi, W1, W2,
                                   pef, hsh, hsl,
                                   WQoh, WQol, WQih, WQil,
                                   WKoh, WKol, WKih, WKil,
                                   WVih, WVil, W1th, W1tl, W2th, W2tl);

    // 2. weight batch: Wc_out (z0), Wc_in (z1), Wv1t (z2), H1 (z3)
    wbatch<<<dim3(16, 32, 4), 256, 0, stream>>>(
        WKoh, WKol, WKih, WKil, WQoh, WQol, WQih, WQil,
        W1th, W1tl, WVih, WVil, hsh, hsl,
        Wbigh, Wbigl, Wv1th, Wv1tl, H1);

    // 3. ubatch: Up split-K2  [512 blocks, 2/CU]
    ubatch<<<dim3(16, 16, 2), 256, 0, stream>>>(hsh, hsl, Wbigh, Wbigl, Up);

    // 4. fused attention over phi -> v (fp32), w (hi/lo)
    phi_attn<<<BB, 512, 0, stream>>>(phi, Up, pef, v, wh, wl);

    // 5. hidden = relu(H1 + w@Wv1t^T + b1)
    hgemm<<<dim3(16, 16), 256, 0, stream>>>(wh, wl, Wv1th, Wv1tl, b1, H1,
                                            hidh, hidl);

    // 6. lgemm split-K2 -> Lp
    lgemm<<<dim3(8, 16, 2), 256, 0, stream>>>(hidh, hidl, W2th, W2tl, Lp);

    // 7. out = softmax(v + Lp0 + Lp1 + b2)
    final_softmax<<<BB, 256, 0, stream>>>(v, Lp, b2, out);
}

// Round 13
// 124.966 us; speedup vs baseline: 1.0497x; 1.0497x over previous
//
#include <hip/hip_runtime.h>
#include <math.h>

// Problem dims
#define BB 512
#define DE 1024
#define DM 1024
#define NA 512
#define NP 256

typedef unsigned short ushort_t;
typedef __attribute__((ext_vector_type(8))) short s8v;   // 8 bf16 (4 VGPRs)
typedef __attribute__((ext_vector_type(4))) float f4v;   // 4 fp32 acc

static __device__ __forceinline__ float4 ld4(const float* p) {
    return *reinterpret_cast<const float4*>(p);
}
static __device__ __forceinline__ void ld8(const float* p, float* d) {
    float4 a = ld4(p), b = ld4(p + 4);
    d[0]=a.x; d[1]=a.y; d[2]=a.z; d[3]=a.w;
    d[4]=b.x; d[5]=b.y; d[6]=b.z; d[7]=b.w;
}

// RNE float -> bf16 bits
__device__ __forceinline__ unsigned bf16h(float x) {
    unsigned u = __float_as_uint(x);
    return (u + 0x7FFFu + ((u >> 16) & 1u)) >> 16;
}
__device__ __forceinline__ float bf16f(unsigned h) { return __uint_as_float(h << 16); }

__device__ __forceinline__ f4v mfma16(s8v a, s8v b, f4v c) {
    return __builtin_amdgcn_mfma_f32_16x16x32_bf16(a, b, c, 0, 0, 0);
}

// Barrier WITHOUT the vmcnt(0) drain (lgkmcnt only — prefetch stays in flight).
__device__ __forceinline__ void softbar() {
    asm volatile("s_waitcnt lgkmcnt(0)" ::: "memory");
    __builtin_amdgcn_s_barrier();
    __builtin_amdgcn_sched_barrier(0);
}

// ================= PREP: PE table (fp32) + weight/h_s hi-lo splits ============
__device__ __forceinline__ void d_ew(const float* __restrict__ W,
                                     ushort_t* __restrict__ Hh,
                                     ushort_t* __restrict__ Hl, int bid) {
    int i = (bid * 256 + threadIdx.x) * 4;
    float4 f = ld4(W + i);
    float ff[4] = {f.x, f.y, f.z, f.w};
    unsigned h[4], l[4];
    #pragma unroll
    for (int q = 0; q < 4; ++q) { h[q] = bf16h(ff[q]); l[q] = bf16h(ff[q] - bf16f(h[q])); }
    *reinterpret_cast<uint2*>(Hh + i) = make_uint2(h[0] | (h[1] << 16), h[2] | (h[3] << 16));
    *reinterpret_cast<uint2*>(Hl + i) = make_uint2(l[0] | (l[1] << 16), l[2] | (l[3] << 16));
}

__device__ __forceinline__ void d_tr(const float* __restrict__ W,
                                     ushort_t* __restrict__ Th,
                                     ushort_t* __restrict__ Tl,
                                     int K, int N, int bid) {
    __shared__ float t[32][33];
    int ntn = N >> 5;
    int kt = bid / ntn, nt = bid - kt * ntn;
    int k0 = kt * 32, n0 = nt * 32;
    int ty = threadIdx.x >> 3, tx = (threadIdx.x & 7) * 4;
    float4 f = ld4(W + (size_t)(k0 + ty) * N + n0 + tx);
    t[ty][tx] = f.x; t[ty][tx + 1] = f.y; t[ty][tx + 2] = f.z; t[ty][tx + 3] = f.w;
    __syncthreads();
    unsigned h[4], l[4];
    #pragma unroll
    for (int q = 0; q < 4; ++q) {
        float x = t[tx + q][ty];
        h[q] = bf16h(x); l[q] = bf16h(x - bf16f(h[q]));
    }
    size_t o = (size_t)(n0 + ty) * K + k0 + tx;
    *reinterpret_cast<uint2*>(Th + o) = make_uint2(h[0] | (h[1] << 16), h[2] | (h[3] << 16));
    *reinterpret_cast<uint2*>(Tl + o) = make_uint2(l[0] | (l[1] << 16), l[2] | (l[3] << 16));
}

__global__ __launch_bounds__(256) void prep(
    const float* __restrict__ h_s, const float* __restrict__ WQo,
    const float* __restrict__ WQi, const float* __restrict__ WKo,
    const float* __restrict__ WKi, const float* __restrict__ WVi,
    const float* __restrict__ W1, const float* __restrict__ W2,
    float* pef, ushort_t* hsh, ushort_t* hsl,
    ushort_t* WQoh, ushort_t* WQol, ushort_t* WQih, ushort_t* WQil,
    ushort_t* WKoh, ushort_t* WKol, ushort_t* WKih, ushort_t* WKil,
    ushort_t* WVih, ushort_t* WVil, ushort_t* W1th, ushort_t* W1tl,
    ushort_t* W2th, ushort_t* W2tl) {
    int bid = blockIdx.x;
    if (bid < 257) {
        int p = bid, i = threadIdx.x;
        const float c = -0.017988946039015984f; // -ln(10000)/512
        float div = expf((float)(2 * i) * c);
        float arg = (float)p * div;
        float2 scv = make_float2(sinf(arg), cosf(arg));
        *reinterpret_cast<float2*>(pef + p * NA + 2 * i) = scv;
        return;
    }
    if ((bid -= 257) < 512)  { d_ew(h_s, hsh, hsl, bid); return; }
    if ((bid -= 512) < 1024) { d_ew(WQo, WQoh, WQol, bid); return; }
    if ((bid -= 1024) < 1024){ d_ew(WQi, WQih, WQil, bid); return; }
    if ((bid -= 1024) < 512) { d_ew(WKo, WKoh, WKol, bid); return; }
    if ((bid -= 512) < 512)  { d_ew(WKi, WKih, WKil, bid); return; }
    if ((bid -= 512) < 512)  { d_ew(WVi, WVih, WVil, bid); return; }
    if ((bid -= 512) < 2048) { d_tr(W1, W1th, W1tl, DE + DM, DM, bid); return; }
    bid -= 2048;               d_tr(W2, W2th, W2tl, DM, NA, bid);
}

// ================= split-bf16 MFMA GEMM tile (all-static dims) ================
template<int M, int N, int K, int KS, int LDA, int LDA2, int LDB, int LDB2,
         int LDC, int BIAS, int RELU, int CFOUT, int CHOUT, int ADDC>
__device__ __forceinline__ void gtile(
    const ushort_t* __restrict__ Ah, const ushort_t* __restrict__ Al,
    const ushort_t* __restrict__ A2h, const ushort_t* __restrict__ A2l,
    const ushort_t* __restrict__ Bh, const ushort_t* __restrict__ Bl,
    const ushort_t* __restrict__ B2h, const ushort_t* __restrict__ B2l,
    const float* __restrict__ bias, const float* __restrict__ Cin,
    float* __restrict__ Cf, ushort_t* __restrict__ Ch, ushort_t* __restrict__ Cl,
    ushort_t* sAh, ushort_t* sAl, ushort_t* sBh, ushort_t* sBl) {
    const int row0 = blockIdx.y * 32, col0 = blockIdx.x * 64;
    if (row0 >= M || col0 >= N) return;
    const int tid = threadIdx.x;

    const int ar = tid >> 3, ak = (tid & 7) * 8;
    const int asi = ar * 64 + (ak ^ ((ar & 7) << 3));
    const int br = tid >> 2, bk = (tid & 3) * 16;
    const int bsw = (br & 7) << 3;
    const int bsi0 = br * 64 + (bk ^ bsw);
    const int bsi1 = br * 64 + ((bk + 8) ^ bsw);

    const int wid = tid >> 6, lane = tid & 63;
    const int wm = wid & 1, wn = wid >> 1;
    const int lm = lane & 15, lk = lane >> 4;
    const int ra = wm * 16 + lm;
    const int rb = wn * 32 + lm;
    const int aswz = (ra & 7) << 3;
    const int bswz = (rb & 7) << 3;

    int4 rah, ral, rb0h, rb1h, rb0l, rb1l;
    auto load = [&](int k0) {
        if (KS < K && k0 >= KS) {
            size_t ao = (size_t)(row0 + ar) * LDA2 + (k0 - KS) + ak;
            rah = *reinterpret_cast<const int4*>(A2h + ao);
            ral = *reinterpret_cast<const int4*>(A2l + ao);
        } else {
            size_t ao = (size_t)(row0 + ar) * LDA + k0 + ak;
            rah = *reinterpret_cast<const int4*>(Ah + ao);
            ral = *reinterpret_cast<const int4*>(Al + ao);
        }
        if (KS < K && k0 >= KS) {
            size_t bo = (size_t)(col0 + br) * LDB2 + (k0 - KS) + bk;
            rb0h = *reinterpret_cast<const int4*>(B2h + bo);
            rb1h = *reinterpret_cast<const int4*>(B2h + bo + 8);
            rb0l = *reinterpret_cast<const int4*>(B2l + bo);
            rb1l = *reinterpret_cast<const int4*>(B2l + bo + 8);
        } else {
            size_t bo = (size_t)(col0 + br) * LDB + k0 + bk;
            rb0h = *reinterpret_cast<const int4*>(Bh + bo);
            rb1h = *reinterpret_cast<const int4*>(Bh + bo + 8);
            rb0l = *reinterpret_cast<const int4*>(Bl + bo);
            rb1l = *reinterpret_cast<const int4*>(Bl + bo + 8);
        }
    };

    f4v acc[2] = {};
    load(0);
    constexpr int NT = K >> 6;
    #pragma unroll
    for (int t = 0; t < NT; ++t) {
        const int co = (t & 1) ? 2048 : 0;
        const int cb = (t & 1) ? 4096 : 0;
        *reinterpret_cast<int4*>(&sAh[co + asi]) = rah;
        *reinterpret_cast<int4*>(&sAl[co + asi]) = ral;
        *reinterpret_cast<int4*>(&sBh[cb + bsi0]) = rb0h;
        *reinterpret_cast<int4*>(&sBh[cb + bsi1]) = rb1h;
        *reinterpret_cast<int4*>(&sBl[cb + bsi0]) = rb0l;
        *reinterpret_cast<int4*>(&sBl[cb + bsi1]) = rb1l;
        if (t + 1 < NT) load((t + 1) << 6);
        softbar();   // lgkmcnt(0)+s_barrier only: prefetch stays in flight
        #pragma unroll
        for (int ks = 0; ks < 2; ++ks) {
            const int ka = (ks * 32 + lk * 8) ^ aswz;
            const int kb = (ks * 32 + lk * 8) ^ bswz;
            s8v a_h = *reinterpret_cast<const s8v*>(&sAh[co + ra * 64 + ka]);
            s8v a_l = *reinterpret_cast<const s8v*>(&sAl[co + ra * 64 + ka]);
            s8v b0h = *reinterpret_cast<const s8v*>(&sBh[cb + rb * 64 + kb]);
            s8v b1h = *reinterpret_cast<const s8v*>(&sBh[cb + (rb + 16) * 64 + kb]);
            s8v b0l = *reinterpret_cast<const s8v*>(&sBl[cb + rb * 64 + kb]);
            s8v b1l = *reinterpret_cast<const s8v*>(&sBl[cb + (rb + 16) * 64 + kb]);
            acc[0] = mfma16(a_h, b0h, acc[0]);
            acc[1] = mfma16(a_h, b1h, acc[1]);
            acc[0] = mfma16(a_h, b0l, acc[0]);
            acc[1] = mfma16(a_h, b1l, acc[1]);
            acc[0] = mfma16(a_l, b0h, acc[0]);
            acc[1] = mfma16(a_l, b1h, acc[1]);
        }
    }

    #pragma unroll
    for (int j = 0; j < 2; ++j) {
        int gc = col0 + wn * 32 + j * 16 + lm;
        float bv = BIAS ? bias[gc] : 0.0f;
        #pragma unroll
        for (int r = 0; r < 4; ++r) {
            int gr = row0 + wm * 16 + lk * 4 + r;
            size_t o = (size_t)gr * LDC + gc;
            float val = acc[j][r] + bv;
            if (ADDC) val += Cin[o];
            if (RELU) val = fmaxf(val, 0.0f);
            if (CFOUT) Cf[o] = val;
            if (CHOUT) {
                unsigned h = bf16h(val);
                Ch[o] = (ushort_t)h;
                Cl[o] = (ushort_t)bf16h(val - bf16f(h));
            }
        }
    }
}

#define GSHARED \
    __shared__ ushort_t sAh[2 * 2048], sAl[2 * 2048]; \
    __shared__ ushort_t sBh[2 * 4096], sBl[2 * 4096];

// ---- weight batch: z0/z1: Wc = WK@WQ^T; z2: Wv1t; z3: H1 = h_s@W1a^T --------
__global__ __launch_bounds__(256) void wbatch(
    const ushort_t* WKoh, const ushort_t* WKol,
    const ushort_t* WKih, const ushort_t* WKil,
    const ushort_t* WQoh, const ushort_t* WQol,
    const ushort_t* WQih, const ushort_t* WQil,
    const ushort_t* W1th, const ushort_t* W1tl,
    const ushort_t* WVih, const ushort_t* WVil,
    const ushort_t* hsh, const ushort_t* hsl,
    ushort_t* Wbigh, ushort_t* Wbigl,
    ushort_t* Wv1th, ushort_t* Wv1tl, float* H1) {
    GSHARED
    const int z = blockIdx.z;
    if (z == 3) {
        gtile<512, 1024, 1024, 1024, 1024, 1, 2048, 1, 1024, 0,0,1,0,0>(
            hsh, hsl, nullptr, nullptr, W1th, W1tl, nullptr, nullptr,
            nullptr, nullptr, H1, nullptr, nullptr, sAh, sAl, sBh, sBl);
    } else if (z == 2) {
        gtile<1024, 512, 1024, 1024, 2048, 1, 1024, 1, 512, 0,0,0,1,0>(
            W1th + 1024, W1tl + 1024, nullptr, nullptr,
            WVih, WVil, nullptr, nullptr,
            nullptr, nullptr, nullptr, Wv1th, Wv1tl, sAh, sAl, sBh, sBl);
    } else {
        const ushort_t* Ah = z ? WKih : WKoh;
        const ushort_t* Al = z ? WKil : WKol;
        const ushort_t* Bh = z ? WQih : WQoh;
        const ushort_t* Bl = z ? WQil : WQol;
        ushort_t* Ch = Wbigh + (size_t)z * 512 * 1024;
        ushort_t* Cl = Wbigl + (size_t)z * 512 * 1024;
        gtile<512, 1024, 1024, 1024, 1024, 1, 1024, 1, 1024, 0,0,0,1,0>(
            Ah, Al, nullptr, nullptr, Bh, Bl, nullptr, nullptr,
            nullptr, nullptr, nullptr, Ch, Cl, sAh, sAl, sBh, sBl);
    }
}

// ---- ubatch: Up[z] = h_s[:,z*512:] @ Wbig[:,z*512:]^T (fp32 partials) --------
__global__ __launch_bounds__(256) void ubatch(
    const ushort_t* hsh, const ushort_t* hsl,
    const ushort_t* Wbigh, const ushort_t* Wbigl,
    float* Up) {
    GSHARED
    const int z = blockIdx.z;
    gtile<512, 1024, 512, 512, 1024, 1, 1024, 1, 1024, 0,0,1,0,0>(
        hsh + z * 512, hsl + z * 512, nullptr, nullptr,
        Wbigh + z * 512, Wbigl + z * 512, nullptr, nullptr,
        nullptr, nullptr, Up + (size_t)z * 512 * 1024, nullptr, nullptr,
        sAh, sAl, sBh, sBl);
}

// ---- hidden = relu(H1 + w@Wv1t^T + b1) (512x1024x512) ------------------------
__global__ __launch_bounds__(256) void hgemm(
    const ushort_t* wh, const ushort_t* wl,
    const ushort_t* Wv1th, const ushort_t* Wv1tl,
    const float* b1, const float* H1,
    ushort_t* hidh, ushort_t* hidl) {
    GSHARED
    gtile<512, 1024, 512, 512, 512, 1, 512, 1, 1024, 1,1,0,1,1>(
        wh, wl, nullptr, nullptr, Wv1th, Wv1tl, nullptr, nullptr,
        b1, H1, nullptr, hidh, hidl, sAh, sAl, sBh, sBl);
}

// ---- lgemm split-K2: Lp[z] = hidden[:,z*512:] @ W2t[:,z*512:]^T (fp32) -------
__global__ __launch_bounds__(256) void lgemm(
    const ushort_t* hidh, const ushort_t* hidl,
    const ushort_t* W2th, const ushort_t* W2tl,
    float* Lp) {
    GSHARED
    const int z = blockIdx.z;
    gtile<512, 512, 512, 512, 1024, 1, 1024, 1, 512, 0,0,1,0,0>(
        hidh + z * 512, hidl + z * 512, nullptr, nullptr,
        W2th + z * 512, W2tl + z * 512, nullptr, nullptr,
        nullptr, nullptr, Lp + (size_t)z * 512 * 512, nullptr, nullptr,
        sAh, sAl, sBh, sBl);
}

// ================= fused attention over phi (barrier-free stream) =============
// Consumes the two ugemm split-K partials (Up0 + Up1) directly.
__global__ __launch_bounds__(512) void phi_attn(
    const float* __restrict__ phi, const float* __restrict__ Up,
    const float* __restrict__ pe, float* __restrict__ v,
    ushort_t* __restrict__ wh, ushort_t* __restrict__ wl) {
    __shared__ float sva[8][512];   // 16 KB
    __shared__ float ssa[8][512];   // 16 KB
    __shared__ float smx[4][8];
    __shared__ float sred[8];
    const int b = blockIdx.x, tid = threadIdx.x;
    const int wave = tid >> 6, lane = tid & 63;
    const float sc = 0.03125f * 1.4426950408889634f;  // 1/sqrt(dm) * log2(e)

    const float* ub0 = Up + (size_t)b * 1024;
    const float* ub1 = ub0 + (size_t)512 * 1024;
    float u8o[8], u8i[8];
    {
        float t0[8], t1[8];
        ld8(ub0 + lane * 8, t0); ld8(ub1 + lane * 8, t1);
        #pragma unroll
        for (int j = 0; j < 8; ++j) u8o[j] = t0[j] + t1[j];
        ld8(ub0 + 512 + lane * 8, t0); ld8(ub1 + 512 + lane * 8, t1);
        #pragma unroll
        for (int j = 0; j < 8; ++j) u8i[j] = t0[j] + t1[j];
    }
    const float* pb = phi + (size_t)b * NP * NA;

    float x0[8], x1[8];
    {
        const float* r = pb + (size_t)(wave * 2) * NA + lane * 8;
        ld8(r, x0); ld8(r + NA, x1);
    }

    float mo = -3.0e38f, mi = -3.0e38f, Zo = 0.f, Zi = 0.f;
    float va[8] = {}, Sa[8] = {};

    for (int c = 0; c < 16; ++c) {
        const int r0 = c * 16 + wave * 2;
        float p0[8], p1[8], p2[8];
        ld8(pe + (size_t)r0 * NA + lane * 8, p0);
        ld8(pe + (size_t)(r0 + 1) * NA + lane * 8, p1);
        ld8(pe + (size_t)(r0 + 2) * NA + lane * 8, p2);
        float so0 = 0.f, si0 = 0.f, so1 = 0.f, si1 = 0.f;
        #pragma unroll
        for (int j = 0; j < 8; ++j) {
            so0 = fmaf(u8o[j], x0[j] + p0[j], so0);
            si0 = fmaf(u8i[j], x0[j] + p1[j], si0);
            so1 = fmaf(u8o[j], x1[j] + p1[j], so1);
            si1 = fmaf(u8i[j], x1[j] + p2[j], si1);
        }
        for (int off = 32; off; off >>= 1) {
            so0 += __shfl_xor(so0, off); si0 += __shfl_xor(si0, off);
            so1 += __shfl_xor(so1, off); si1 += __shfl_xor(si1, off);
        }
        so0 *= sc; si0 *= sc; so1 *= sc; si1 *= sc;
        // prefetch next chunk rows (in flight under the exp/accumulate VALU)
        float n0[8], n1[8];
        if (c < 15) {
            const float* r = pb + (size_t)((c + 1) * 16 + wave * 2) * NA + lane * 8;
            ld8(r, n0); ld8(r + NA, n1);
        }
        float nmo = fmaxf(mo, fmaxf(so0, so1));
        float nmi = fmaxf(mi, fmaxf(si0, si1));
        float fo = exp2f(mo - nmo), fi = exp2f(mi - nmi);
        float e00 = exp2f(so0 - nmo), e01 = exp2f(so1 - nmo);
        float e10 = exp2f(si0 - nmi), e11 = exp2f(si1 - nmi);
        mo = nmo; mi = nmi;
        Zo = Zo * fo + (e00 + e01);
        Zi = Zi * fi + (e10 + e11);
        #pragma unroll
        for (int j = 0; j < 8; ++j) {
            va[j] = fmaf(va[j], fo, fmaf(e00, x0[j], e01 * x1[j]));
            Sa[j] = fmaf(Sa[j], fi, fmaf(e10, x0[j], e11 * x1[j]));
        }
        if (c < 15) {
            #pragma unroll
            for (int j = 0; j < 8; ++j) { x0[j] = n0[j]; x1[j] = n1[j]; }
        }
    }

    // ---- flash merge across the 8 waves ----
    if (lane == 0) { smx[0][wave] = mo; smx[1][wave] = mi; }
    __syncthreads();
    float gmo = smx[0][0], gmi = smx[1][0];
    #pragma unroll
    for (int w2 = 1; w2 < 8; ++w2) {
        gmo = fmaxf(gmo, smx[0][w2]); gmi = fmaxf(gmi, smx[1][w2]);
    }
    float fo = exp2f(mo - gmo), fi = exp2f(mi - gmi);
    {
        float4 a0 = {va[0]*fo, va[1]*fo, va[2]*fo, va[3]*fo};
        float4 a1 = {va[4]*fo, va[5]*fo, va[6]*fo, va[7]*fo};
        *reinterpret_cast<float4*>(&sva[wave][lane * 8]) = a0;
        *reinterpret_cast<float4*>(&sva[wave][lane * 8 + 4]) = a1;
        float4 s0v = {Sa[0]*fi, Sa[1]*fi, Sa[2]*fi, Sa[3]*fi};
        float4 s1v = {Sa[4]*fi, Sa[5]*fi, Sa[6]*fi, Sa[7]*fi};
        *reinterpret_cast<float4*>(&ssa[wave][lane * 8]) = s0v;
        *reinterpret_cast<float4*>(&ssa[wave][lane * 8 + 4]) = s1v;
    }
    if (lane == 0) { smx[2][wave] = Zo * fo; smx[3][wave] = Zi * fi; }
    __syncthreads();
    float Zot = 0.f, Zit = 0.f;
    #pragma unroll
    for (int w2 = 0; w2 < 8; ++w2) { Zot += smx[2][w2]; Zit += smx[3][w2]; }
    float vs = 0.f, Ss = 0.f;
    #pragma unroll
    for (int w2 = 0; w2 < 8; ++w2) { vs += sva[w2][tid]; Ss += ssa[w2][tid]; }
    float vt = vs / Zot;
    v[(size_t)b * NA + tid] = vt;

    // ---- in-head row-0 fixup -> w ----
    float uit = ub0[512 + tid] + ub1[512 + tid];
    float part = uit * (vt + pe[tid]);   // pe row 0
    for (int off = 32; off; off >>= 1) part += __shfl_xor(part, off);
    if (lane == 0) sred[wave] = part;
    __syncthreads();
    float dot = ((sred[0] + sred[1]) + (sred[2] + sred[3]))
              + ((sred[4] + sred[5]) + (sred[6] + sred[7]));
    float s0 = dot * sc;
    float e0 = exp2f(s0 - gmi);
    float iZ = 1.0f / (Zit + e0);
    float wt = (e0 * vt + Ss) * iZ;
    unsigned h = bf16h(wt);
    wh[(size_t)b * NA + tid] = (ushort_t)h;
    wl[(size_t)b * NA + tid] = (ushort_t)bf16h(wt - bf16f(h));
}

// ---------------- final: out = softmax(v + Lp0 + Lp1 + b2) --------------------
__global__ __launch_bounds__(256) void final_softmax(const float* __restrict__ v,
                                                     const float* __restrict__ Lp,
                                                     const float* __restrict__ b2,
                                                     float* __restrict__ out) {
    __shared__ float smem[4];
    int b = blockIdx.x, t = threadIdx.x;
    int lane = t & 63, w = t >> 6;
    const float* l0 = Lp + (size_t)b * 512;
    const float* l1 = l0 + (size_t)512 * 512;
    float z0 = l0[t] + l1[t] + b2[t] + v[(size_t)b * NA + t];
    float z1 = l0[t + 256] + l1[t + 256] + b2[t + 256] + v[(size_t)b * NA + 256 + t];
    float m = fmaxf(z0, z1);
    for (int off = 32; off; off >>= 1) m = fmaxf(m, __shfl_xor(m, off));
    __syncthreads();
    if (lane == 0) smem[w] = m;
    __syncthreads();
    m = fmaxf(fmaxf(smem[0], smem[1]), fmaxf(smem[2], smem[3]));
    float e0 = expf(z0 - m), e1 = expf(z1 - m);
    float s = e0 + e1;
    for (int off = 32; off; off >>= 1) s += __shfl_xor(s, off);
    __syncthreads();
    if (lane == 0) smem[w] = s;
    __syncthreads();
    float Z = (smem[0] + smem[1]) + (smem[2] + smem[3]);
    out[(size_t)b * NA + t] = e0 / Z;
    out[(size_t)b * NA + 256 + t] = e1 / Z;
}

// ---------------- launch ------------------------------------------------------
extern "C" void kernel_launch(void* const* d_in, const int* in_sizes, int n_in,
                              void* d_out, int out_size, void* d_ws, size_t ws_size,
                              hipStream_t stream) {
    const float* h_s = (const float*)d_in[0];
    const float* phi = (const float*)d_in[1];
    const float* WQo = (const float*)d_in[2];
    const float* WKo = (const float*)d_in[3];
    const float* WQi = (const float*)d_in[4];
    const float* WKi = (const float*)d_in[5];
    const float* WVi = (const float*)d_in[6];
    const float* W1  = (const float*)d_in[7];
    const float* b1  = (const float*)d_in[8];
    const float* W2  = (const float*)d_in[9];
    const float* b2  = (const float*)d_in[10];
    float* out = (float*)d_out;
    float* wsf = (float*)d_ws;

    size_t off = 0;
    auto af = [&](size_t n) { float* p = wsf + off; off += (n + 3) & ~(size_t)3; return p; };
    auto au = [&](size_t n) { ushort_t* p = (ushort_t*)(wsf + off); off += ((n / 2) + 3) & ~(size_t)3; return p; };

    float*    pef   = af(257 * NA);
    ushort_t* hsh   = au((size_t)BB*DE);     ushort_t* hsl   = au((size_t)BB*DE);
    ushort_t* WQoh  = au((size_t)DE*DM);     ushort_t* WQol  = au((size_t)DE*DM);
    ushort_t* WQih  = au((size_t)DE*DM);     ushort_t* WQil  = au((size_t)DE*DM);
    ushort_t* WKoh  = au((size_t)NA*DM);     ushort_t* WKol  = au((size_t)NA*DM);
    ushort_t* WKih  = au((size_t)NA*DM);     ushort_t* WKil  = au((size_t)NA*DM);
    ushort_t* WVih  = au((size_t)NA*DM);     ushort_t* WVil  = au((size_t)NA*DM);
    ushort_t* W1th  = au((size_t)DM*(DE+DM));ushort_t* W1tl  = au((size_t)DM*(DE+DM));
    ushort_t* W2th  = au((size_t)NA*DM);     ushort_t* W2tl  = au((size_t)NA*DM);
    ushort_t* Wbigh = au((size_t)1024*DE);   ushort_t* Wbigl = au((size_t)1024*DE);
    ushort_t* Wv1th = au((size_t)DM*NA);     ushort_t* Wv1tl = au((size_t)DM*NA);
    float*    Up    = af((size_t)2 * BB * 1024);   // ugemm split-K partials
    float*    H1    = af((size_t)BB * DM);         // h_s @ W1a^T
    float*    Lp    = af((size_t)2 * BB * NA);     // lgemm split-K partials
    float*    v     = af((size_t)BB * NA);
    ushort_t* wh    = au((size_t)BB*NA);     ushort_t* wl    = au((size_t)BB*NA);
    ushort_t* hidh  = au((size_t)BB*DM);     ushort_t* hidl  = au((size_t)BB*DM);

    // 1. prep
    prep<<<6913, 256, 0, stream>>>(h_s, WQo, WQi, WKo, WKi, WVi, W1, W2,
                                   pef, hsh, hsl,
                                   WQoh, WQol, WQih, WQil,
                                   WKoh, WKol, WKih, WKil,
                                   WVih, WVil, W1th, W1tl, W2th, W2tl);

    // 2. weight batch: Wc_out (z0), Wc_in (z1), Wv1t (z2), H1 (z3)
    wbatch<<<dim3(16, 32, 4), 256, 0, stream>>>(
        WKoh, WKol, WKih, WKil, WQoh, WQol, WQih, WQil,
        W1th, W1tl, WVih, WVil, hsh, hsl,
        Wbigh, Wbigl, Wv1th, Wv1tl, H1);

    // 3. ubatch: Up split-K2  [512 blocks, 2/CU]
    ubatch<<<dim3(16, 16, 2), 256, 0, stream>>>(hsh, hsl, Wbigh, Wbigl, Up);

    // 4. fused attention over phi (sums Up partials) -> v (fp32), w (hi/lo)
    phi_attn<<<BB, 512, 0, stream>>>(phi, Up, pef, v, wh, wl);

    // 5. hidden = relu(H1 + w@Wv1t^T + b1)   [K=512 only on critical path]
    hgemm<<<dim3(16, 16), 256, 0, stream>>>(wh, wl, Wv1th, Wv1tl, b1, H1,
                                            hidh, hidl);

    // 6. lgemm split-K2 -> Lp  [256 blocks]
    lgemm<<<dim3(8, 16, 2), 256, 0, stream>>>(hidh, hidl, W2th, W2tl, Lp);

    // 7. out = softmax(v + Lp0 + Lp1 + b2)
    final_softmax<<<BB, 256, 0, stream>>>(v, Lp, b2, out);
}